// Round 8
// baseline (387.591 us; speedup 1.0000x reference)
//
#include <hip/hip_runtime.h>
#include <math.h>

#define DMODEL 1024
#define NHEADS 16
#define DKDIM  64
#define SEQLEN 2048
#define NBATCH 4
#define MTOT   (NBATCH * SEQLEN)   // 8192

typedef __attribute__((ext_vector_type(8)))  short short8;
typedef __attribute__((ext_vector_type(4)))  float f32x4;
typedef __attribute__((ext_vector_type(16))) float f32x16;

__device__ __forceinline__ unsigned short f2bf(float x) {
    unsigned u = __builtin_bit_cast(unsigned, x);
    unsigned r = (u + 0x7fffu + ((u >> 16) & 1u)) >> 16;
    return (unsigned short)r;
}

__device__ __forceinline__ void gload16(const void* g, void* l) {
    __builtin_amdgcn_global_load_lds(
        (const __attribute__((address_space(1))) void*)g,
        (__attribute__((address_space(3))) void*)l, 16, 0, 0);
}

// ============ convert x (f32 -> bf16 flat) ============
__global__ __launch_bounds__(256)
void convert_x_kernel(const float* __restrict__ x, unsigned short* __restrict__ xb)
{
    const size_t i = ((size_t)blockIdx.x * 256 + threadIdx.x) * 8;
    const float4 a = *(const float4*)&x[i];
    const float4 b = *(const float4*)&x[i + 4];
    union { unsigned short u[8]; uint4 q; } p;
    p.u[0] = f2bf(a.x); p.u[1] = f2bf(a.y); p.u[2] = f2bf(a.z); p.u[3] = f2bf(a.w);
    p.u[4] = f2bf(b.x); p.u[5] = f2bf(b.y); p.u[6] = f2bf(b.z); p.u[7] = f2bf(b.w);
    *(uint4*)&xb[i] = p.q;
}

// ============ convert + transpose W: W[k][n] f32 -> Wt[n][k] bf16 ============
__global__ __launch_bounds__(256)
void convert_w_kernel(const float* __restrict__ W0, const float* __restrict__ W1,
                      const float* __restrict__ W2, const float* __restrict__ W3,
                      unsigned short* __restrict__ wt)
{
    const int z = blockIdx.z;
    const float* W = (z == 0) ? W0 : (z == 1) ? W1 : (z == 2) ? W2 : W3;
    unsigned short* dst = wt + (size_t)z * DMODEL * DMODEL;
    const int n0 = blockIdx.x * 64, k0 = blockIdx.y * 64;
    __shared__ float T[64][65];
    const int t = threadIdx.x;
    const int r0 = t >> 4, c0 = (t & 15) << 2;
#pragma unroll
    for (int u = 0; u < 4; ++u) {
        const float4 wv = *(const float4*)&W[(size_t)(k0 + r0 + u * 16) * DMODEL + n0 + c0];
        T[c0 + 0][r0 + u * 16] = wv.x;
        T[c0 + 1][r0 + u * 16] = wv.y;
        T[c0 + 2][r0 + u * 16] = wv.z;
        T[c0 + 3][r0 + u * 16] = wv.w;
    }
    __syncthreads();
    const int rn = t >> 2, ck = (t & 3) << 4;
    union { unsigned short u16[16]; uint4 q[2]; } pk;
#pragma unroll
    for (int e = 0; e < 16; ++e) pk.u16[e] = f2bf(T[rn][ck + e]);
    *(uint4*)&dst[(size_t)(n0 + rn) * DMODEL + k0 + ck]     = pk.q[0];
    *(uint4*)&dst[(size_t)(n0 + rn) * DMODEL + k0 + ck + 8] = pk.q[1];
}

// ============ bf16 MFMA GEMM ============
// OMODE 0: bf16 flat [m][n];  OMODE 1: bf16 V-transposed [B,H,Dk,S];  OMODE 2: f32 flat.
// Grid must be (8, 64): XCD-swizzled internally (nwg=512, bijective since 512%8==0).
template<int OMODE>
__device__ __forceinline__
void gemm_core(const unsigned short* __restrict__ A, const unsigned short* __restrict__ Bt,
               const float* __restrict__ bias, void* __restrict__ outv, const float scl)
{
    __shared__ __align__(16) char As[128 * 128];
    __shared__ __align__(16) char Bs[128 * 128];

    const int t  = threadIdx.x;
    const int l  = t & 63, w = t >> 6;
    const int g  = (l >> 4), lr = l & 15;
    const int wr = w >> 1, wc = w & 1;
    const int swz = (lr & 7) << 4;

    // XCD-aware swizzle (T1): each XCD gets 8 consecutive m-panels x all n-tiles.
    const int flat = (blockIdx.y << 3) | blockIdx.x;          // 0..511
    const int sid  = ((flat & 7) << 6) | (flat >> 3);
    const int m0 = (sid >> 3) << 7;
    const int n0 = (sid & 7) << 7;

    f32x4 acc[4][4];
#pragma unroll
    for (int i = 0; i < 4; ++i)
#pragma unroll
        for (int j = 0; j < 4; ++j) acc[i][j] = (f32x4){0.f, 0.f, 0.f, 0.f};

    for (int k0 = 0; k0 < DMODEL; k0 += 64) {
        __syncthreads();
#pragma unroll
        for (int qd = 0; qd < 4; ++qd) {
            const int o   = (t + qd * 256) << 4;
            const int row = o >> 7;
            const int c   = (o & 127) ^ ((row & 7) << 4);
            gload16((const char*)A  + (((size_t)(m0 + row) * DMODEL + k0) << 1) + c, As + o);
            gload16((const char*)Bt + (((size_t)(n0 + row) * DMODEL + k0) << 1) + c, Bs + o);
        }
        __syncthreads();

        short8 af[4][2], bf[4][2];
#pragma unroll
        for (int i = 0; i < 4; ++i)
#pragma unroll
            for (int kk = 0; kk < 2; ++kk) {
                const int off = (kk * 64 + g * 16) ^ swz;
                af[i][kk] = *(const short8*)(As + (wr * 64 + i * 16 + lr) * 128 + off);
                bf[i][kk] = *(const short8*)(Bs + (wc * 64 + i * 16 + lr) * 128 + off);
            }
        __builtin_amdgcn_s_setprio(1);
#pragma unroll
        for (int kk = 0; kk < 2; ++kk)
#pragma unroll
            for (int i = 0; i < 4; ++i)
#pragma unroll
                for (int j = 0; j < 4; ++j)
                    acc[i][j] = __builtin_amdgcn_mfma_f32_16x16x32_bf16(
                        af[i][kk], bf[j][kk], acc[i][j], 0, 0, 0);
        __builtin_amdgcn_s_setprio(0);
    }

    float bj[4];
#pragma unroll
    for (int j = 0; j < 4; ++j) bj[j] = bias[n0 + wc * 64 + j * 16 + lr];

#pragma unroll
    for (int i = 0; i < 4; ++i)
#pragma unroll
        for (int j = 0; j < 4; ++j) {
            const int mb = m0 + wr * 64 + i * 16 + g * 4;
            const int n  = n0 + wc * 64 + j * 16 + lr;
            float v[4];
#pragma unroll
            for (int r = 0; r < 4; ++r) v[r] = (acc[i][j][r] + bj[j]) * scl;
            if (OMODE == 0) {
                unsigned short* outp = (unsigned short*)outv;
#pragma unroll
                for (int r = 0; r < 4; ++r)
                    outp[(size_t)(mb + r) * DMODEL + n] = f2bf(v[r]);
            } else if (OMODE == 1) {
                unsigned short* outp = (unsigned short*)outv;
                const int b = mb >> 11, s = mb & (SEQLEN - 1);
                const size_t idx = (((size_t)(b * NHEADS + (n >> 6)) * DKDIM + (n & 63)) << 11) + s;
                uint2 pk;
                pk.x = (unsigned)f2bf(v[0]) | ((unsigned)f2bf(v[1]) << 16);
                pk.y = (unsigned)f2bf(v[2]) | ((unsigned)f2bf(v[3]) << 16);
                *(uint2*)&outp[idx] = pk;
            } else {
                float* outp = (float*)outv;
#pragma unroll
                for (int r = 0; r < 4; ++r)
                    outp[(size_t)(mb + r) * DMODEL + n] = v[r];
            }
        }
}

#define QSCALE 0.1803368801111137f   // 0.125 * log2(e): scores come out in log2 units

__global__ __launch_bounds__(256)
void qkv_gemm_kernel(const unsigned short* __restrict__ xb, const unsigned short* __restrict__ wt,
                     const float* __restrict__ bq, const float* __restrict__ bk,
                     const float* __restrict__ bv,
                     unsigned short* __restrict__ Qb, unsigned short* __restrict__ Kb,
                     unsigned short* __restrict__ Vt)
{
    if (blockIdx.z == 0)      gemm_core<0>(xb, wt,                      bq, Qb, QSCALE);
    else if (blockIdx.z == 1) gemm_core<0>(xb, wt + DMODEL * DMODEL,     bk, Kb, 1.0f);
    else                      gemm_core<1>(xb, wt + 2 * DMODEL * DMODEL, bv, Vt, 1.0f);
}

__global__ __launch_bounds__(256)
void out_gemm_kernel(const unsigned short* __restrict__ ctx, const unsigned short* __restrict__ wt,
                     const float* __restrict__ bo, float* __restrict__ out)
{
    gemm_core<2>(ctx, wt + 3 * DMODEL * DMODEL, bo, out, 1.0f);
}

// ============ bf16 MFMA flash attention, pf-carried software pipeline ============
// 512 thr = 8 waves, 32 q/wave, KV tiles of 64, QUAD-buffered counted-vmcnt staging.
// body(t): vmcnt(2); barrier; stage(t+2); QK(t) [MFMA]; exp/cvt(t)->pf_cur [VALU];
//          PV(t-1) w/ pf_prev [MFMA, independent of exp(t) => pipes overlap].
// V re-read from LDS at PV time => only pf (16 VGPR) carried. Hand-unrolled x2.
__device__ __forceinline__
void qk_full(const char* __restrict__ Kbuf, const short8 (&qf)[4],
             f32x16& s0, f32x16& s1, int q32, int hi, int swz)
{
#pragma unroll
    for (int r = 0; r < 16; ++r) { s0[r] = 0.f; s1[r] = 0.f; }
    short8 kf0[4], kf1[4];
#pragma unroll
    for (int kk = 0; kk < 4; ++kk) {
        kf0[kk] = *(const short8*)(Kbuf + q32 * 128 + ((kk * 32 + hi * 16) ^ swz));
        kf1[kk] = *(const short8*)(Kbuf + (32 + q32) * 128 + ((kk * 32 + hi * 16) ^ swz));
    }
    __builtin_amdgcn_s_setprio(1);
#pragma unroll
    for (int kk = 0; kk < 4; ++kk)
        s0 = __builtin_amdgcn_mfma_f32_32x32x16_bf16(kf0[kk], qf[kk], s0, 0, 0, 0);
#pragma unroll
    for (int kk = 0; kk < 4; ++kk)
        s1 = __builtin_amdgcn_mfma_f32_32x32x16_bf16(kf1[kk], qf[kk], s1, 0, 0, 0);
    __builtin_amdgcn_s_setprio(0);
}

__device__ __forceinline__
void exp_cvt(f32x16& s0, f32x16& s1, short8 (&pf)[4])
{
#pragma unroll
    for (int r = 0; r < 16; ++r) s0[r] = __builtin_amdgcn_exp2f(s0[r]);
#pragma unroll
    for (int r = 0; r < 16; ++r) s1[r] = __builtin_amdgcn_exp2f(s1[r]);
#pragma unroll
    for (int ks = 0; ks < 4; ++ks) {
        const f32x16& st = (ks < 2) ? s0 : s1;
        const int bse = (ks & 1) * 8;
        unsigned wA0, wA1, wB0, wB1;
        asm("v_cvt_pk_bf16_f32 %0, %1, %2" : "=v"(wA0) : "v"(st[bse + 0]), "v"(st[bse + 1]));
        asm("v_cvt_pk_bf16_f32 %0, %1, %2" : "=v"(wA1) : "v"(st[bse + 2]), "v"(st[bse + 3]));
        asm("v_cvt_pk_bf16_f32 %0, %1, %2" : "=v"(wB0) : "v"(st[bse + 4]), "v"(st[bse + 5]));
        asm("v_cvt_pk_bf16_f32 %0, %1, %2" : "=v"(wB1) : "v"(st[bse + 6]), "v"(st[bse + 7]));
        asm volatile("v_permlane32_swap_b32 %0, %1" : "+v"(wA0), "+v"(wB0));
        asm volatile("v_permlane32_swap_b32 %0, %1" : "+v"(wA1), "+v"(wB1));
        union { unsigned u[4]; short8 s8; } pk;
        pk.u[0] = wA0; pk.u[1] = wA1; pk.u[2] = wB0; pk.u[3] = wB1;
        pf[ks] = pk.s8;
    }
}

__device__ __forceinline__
void pv_full(const char* __restrict__ Vbuf, const short8 (&pf)[4], const short8 ones,
             f32x16 (&po)[2], f32x16& po_l, int q32, int hi, int swz)
{
#pragma unroll
    for (int ks = 0; ks < 4; ++ks) {
        const short8 vf0 = *(const short8*)(Vbuf + q32 * 128 + ((ks * 32 + hi * 16) ^ swz));
        const short8 vf1 = *(const short8*)(Vbuf + (32 + q32) * 128 + ((ks * 32 + hi * 16) ^ swz));
        __builtin_amdgcn_s_setprio(1);
        po[0] = __builtin_amdgcn_mfma_f32_32x32x16_bf16(vf0, pf[ks], po[0], 0, 0, 0);
        po[1] = __builtin_amdgcn_mfma_f32_32x32x16_bf16(vf1, pf[ks], po[1], 0, 0, 0);
        po_l  = __builtin_amdgcn_mfma_f32_32x32x16_bf16(ones, pf[ks], po_l,  0, 0, 0);
        __builtin_amdgcn_s_setprio(0);
    }
}

__global__ __launch_bounds__(512, 4)
void attn_kernel(const unsigned short* __restrict__ Qb, const unsigned short* __restrict__ Kb,
                 const unsigned short* __restrict__ Vt, unsigned short* __restrict__ ctx)
{
    __shared__ __align__(16) char smem[65536];   // K bufs [0,32K) x4, V bufs [32K,64K) x4

    const int t   = threadIdx.x;
    const int l   = t & 63, w = t >> 6;
    const int q32 = l & 31, hi = l >> 5;
    const int swz = (q32 & 7) << 4;

    // XCD-aware swizzle (T1): each XCD gets 8 complete heads (K/V = 4MB = L2-resident).
    const int flat = (blockIdx.y << 3) | blockIdx.x;          // 0..511
    const int sid  = ((flat & 7) << 6) | (flat >> 3);
    const int qt = sid & 7;
    const int bh = sid >> 3;
    const int b  = bh >> 4, h = bh & 15;
    const int coln = h * DKDIM;

    const size_t qrow  = (size_t)b * SEQLEN + qt * 256 + w * 32 + q32;
    const size_t krow0 = (size_t)b * SEQLEN;
    const size_t vbase = (size_t)(b * NHEADS + h) * DKDIM * SEQLEN;

    // Q fragments in registers (pre-scaled by 0.125*log2e in projection)
    short8 qf[4];
#pragma unroll
    for (int kk = 0; kk < 4; ++kk)
        qf[kk] = *(const short8*)(Qb + qrow * DMODEL + coln + kk * 16 + hi * 8);

    short8 ones;
#pragma unroll
    for (int e = 0; e < 8; ++e) ones[e] = (short)0x3F80;   // bf16 1.0

    f32x16 po[2], po_l;
#pragma unroll
    for (int r = 0; r < 16; ++r) { po[0][r] = 0.f; po[1][r] = 0.f; po_l[r] = 0.f; }

    const int so   = t << 4;             // staging offset, 0..8191
    const int srow = so >> 7;
    const int sc_  = (so & 127) ^ ((srow & 7) << 4);

#define KBUF(i) (smem + (i) * 8192)
#define VBUF(i) (smem + 32768 + (i) * 8192)
#define STAGE(bufidx, kt)                                                                    \
    do {                                                                                     \
        gload16((const char*)Kb + (((krow0 + (kt) * 64 + srow) * DMODEL + coln) << 1) + sc_, \
                KBUF(bufidx) + so);                                                          \
        gload16((const char*)Vt + ((vbase + (size_t)srow * SEQLEN + (kt) * 64) << 1) + sc_,  \
                VBUF(bufidx) + so);                                                          \
    } while (0)

    f32x16 s0, s1;
    short8 pfA[4], pfB[4];

    STAGE(0, 0);
    STAGE(1, 1);

    // ---- body 0 (no PV yet): writes pfA ----
    asm volatile("s_waitcnt vmcnt(2)" ::: "memory");
    __builtin_amdgcn_s_barrier();
    STAGE(2, 2);
    qk_full(KBUF(0), qf, s0, s1, q32, hi, swz);
    exp_cvt(s0, s1, pfA);

    // ---- main loop: bodies 1..30, hand-unrolled x2 (pfA/pfB rotation) ----
#pragma unroll 1
    for (int kt = 1; kt < 31; kt += 2) {
        // body kt: prev=pfA, writes pfB
        asm volatile("s_waitcnt vmcnt(2)" ::: "memory");
        __builtin_amdgcn_s_barrier();
        STAGE((kt + 2) & 3, kt + 2);                 // kt<=29 -> kt+2<=31, always valid
        qk_full(KBUF(kt & 3), qf, s0, s1, q32, hi, swz);
        exp_cvt(s0, s1, pfB);                        // VALU  } overlap:
        pv_full(VBUF((kt - 1) & 3), pfA, ones, po, po_l, q32, hi, swz);   // MFMA }

        // body kt+1: prev=pfB, writes pfA
        asm volatile("s_waitcnt vmcnt(2)" ::: "memory");
        __builtin_amdgcn_s_barrier();
        if (kt + 3 < 32) STAGE((kt + 3) & 3, kt + 3);
        qk_full(KBUF((kt + 1) & 3), qf, s0, s1, q32, hi, swz);
        exp_cvt(s0, s1, pfA);
        pv_full(VBUF(kt & 3), pfB, ones, po, po_l, q32, hi, swz);
    }

    // ---- tail body 31: prev=pfA (tile 30), writes pfB; then final PV(31) ----
    asm volatile("s_waitcnt vmcnt(0)" ::: "memory");
    __builtin_amdgcn_s_barrier();
    qk_full(KBUF(3), qf, s0, s1, q32, hi, swz);          // 31 & 3 = 3
    exp_cvt(s0, s1, pfB);
    pv_full(VBUF(2), pfA, ones, po, po_l, q32, hi, swz); // 30 & 3 = 2
    pv_full(VBUF(3), pfB, ones, po, po_l, q32, hi, swz);

    __syncthreads();                      // before smem reuse in epilogue

    // ---- epilogue: normalize (lsum = po_l, all rows equal), transpose, write ----
    const float inv = 1.0f / po_l[0];
    char* T = smem + w * 4096;            // per-wave [32 q][64 d] bf16, swizzled
#pragma unroll
    for (int i = 0; i < 2; ++i)
#pragma unroll
        for (int g4 = 0; g4 < 4; ++g4) {
            const int d0 = i * 32 + g4 * 8 + hi * 4;
            uint2 pk;
            pk.x = (unsigned)f2bf(po[i][g4 * 4 + 0] * inv) | ((unsigned)f2bf(po[i][g4 * 4 + 1] * inv) << 16);
            pk.y = (unsigned)f2bf(po[i][g4 * 4 + 2] * inv) | ((unsigned)f2bf(po[i][g4 * 4 + 3] * inv) << 16);
            *(uint2*)(T + ((q32 * 128 + d0 * 2) ^ swz)) = pk;
        }
    __syncthreads();
#pragma unroll
    for (int pass = 0; pass < 4; ++pass) {
        const int o   = (l + pass * 64) << 4;    // 0..4095
        const int row = o >> 7;
        const int c   = o & 127;
        const uint4 val = *(const uint4*)(T + (o ^ ((row & 7) << 4)));
        const size_t token = (size_t)b * SEQLEN + qt * 256 + w * 32 + row;
        *(uint4*)&ctx[token * DMODEL + coln + (c >> 1)] = val;
    }
#undef STAGE
#undef KBUF
#undef VBUF
}

extern "C" void kernel_launch(void* const* d_in, const int* in_sizes, int n_in,
                              void* d_out, int out_size, void* d_ws, size_t ws_size,
                              hipStream_t stream)
{
    const float* x  = (const float*)d_in[0];
    const float* Wq = (const float*)d_in[1];
    const float* bq = (const float*)d_in[2];
    const float* Wk = (const float*)d_in[3];
    const float* bk = (const float*)d_in[4];
    const float* Wv = (const float*)d_in[5];
    const float* bv = (const float*)d_in[6];
    const float* Wo = (const float*)d_in[7];
    const float* bo = (const float*)d_in[8];
    float* out = (float*)d_out;

    const size_t NE = (size_t)MTOT * DMODEL;
    unsigned short* xb  = (unsigned short*)d_ws;
    unsigned short* wt  = xb  + NE;
    unsigned short* Qb  = wt  + (size_t)4 * DMODEL * DMODEL;
    unsigned short* Kb  = Qb  + NE;
    unsigned short* Vt  = Kb  + NE;
    unsigned short* ctx = Vt  + NE;

    convert_x_kernel<<<dim3(NE / (256 * 8)), 256, 0, stream>>>(x, xb);
    convert_w_kernel<<<dim3(16, 16, 4), 256, 0, stream>>>(Wq, Wk, Wv, Wo, wt);
    qkv_gemm_kernel<<<dim3(8, 64, 3), 256, 0, stream>>>(xb, wt, bq, bk, bv, Qb, Kb, Vt);
    attn_kernel<<<dim3(SEQLEN / 256, NBATCH * NHEADS), dim3(512), 0, stream>>>(Qb, Kb, Vt, ctx);
    out_gemm_kernel<<<dim3(8, 64), 256, 0, stream>>>(ctx, wt, bo, out);
}

// Round 12
// 178.329 us; speedup vs baseline: 2.1735x; 2.1735x over previous
//
#include <hip/hip_runtime.h>
#include <math.h>

#define DMODEL 1024
#define NHEADS 16
#define DKDIM  64
#define SEQLEN 2048
#define NBATCH 4
#define MTOT   (NBATCH * SEQLEN)   // 8192

// NOTE (rounds 8-11 dead end): a pf-carried cross-body pipeline (PV(t-1) overlapping
// exp(t)) failed bit-identically (absmax 5.14e-2) under three different sync schemes,
// including plain __syncthreads quad-buffering. Cause never identified; structure
// abandoned. Do not retry without an offline refcheck harness. This file is the
// verified round-7 structure: PV in-body, triple-buffer, vmcnt(2) counted staging.

typedef __attribute__((ext_vector_type(8)))  short short8;
typedef __attribute__((ext_vector_type(4)))  float f32x4;
typedef __attribute__((ext_vector_type(16))) float f32x16;

__device__ __forceinline__ unsigned short f2bf(float x) {
    unsigned u = __builtin_bit_cast(unsigned, x);
    unsigned r = (u + 0x7fffu + ((u >> 16) & 1u)) >> 16;
    return (unsigned short)r;
}

__device__ __forceinline__ void gload16(const void* g, void* l) {
    __builtin_amdgcn_global_load_lds(
        (const __attribute__((address_space(1))) void*)g,
        (__attribute__((address_space(3))) void*)l, 16, 0, 0);
}

// ============ convert x (f32 -> bf16 flat) ============
__global__ __launch_bounds__(256)
void convert_x_kernel(const float* __restrict__ x, unsigned short* __restrict__ xb)
{
    const size_t i = ((size_t)blockIdx.x * 256 + threadIdx.x) * 8;
    const float4 a = *(const float4*)&x[i];
    const float4 b = *(const float4*)&x[i + 4];
    union { unsigned short u[8]; uint4 q; } p;
    p.u[0] = f2bf(a.x); p.u[1] = f2bf(a.y); p.u[2] = f2bf(a.z); p.u[3] = f2bf(a.w);
    p.u[4] = f2bf(b.x); p.u[5] = f2bf(b.y); p.u[6] = f2bf(b.z); p.u[7] = f2bf(b.w);
    *(uint4*)&xb[i] = p.q;
}

// ============ convert + transpose W: W[k][n] f32 -> Wt[n][k] bf16 ============
__global__ __launch_bounds__(256)
void convert_w_kernel(const float* __restrict__ W0, const float* __restrict__ W1,
                      const float* __restrict__ W2, const float* __restrict__ W3,
                      unsigned short* __restrict__ wt)
{
    const int z = blockIdx.z;
    const float* W = (z == 0) ? W0 : (z == 1) ? W1 : (z == 2) ? W2 : W3;
    unsigned short* dst = wt + (size_t)z * DMODEL * DMODEL;
    const int n0 = blockIdx.x * 64, k0 = blockIdx.y * 64;
    __shared__ float T[64][65];
    const int t = threadIdx.x;
    const int r0 = t >> 4, c0 = (t & 15) << 2;
#pragma unroll
    for (int u = 0; u < 4; ++u) {
        const float4 wv = *(const float4*)&W[(size_t)(k0 + r0 + u * 16) * DMODEL + n0 + c0];
        T[c0 + 0][r0 + u * 16] = wv.x;
        T[c0 + 1][r0 + u * 16] = wv.y;
        T[c0 + 2][r0 + u * 16] = wv.z;
        T[c0 + 3][r0 + u * 16] = wv.w;
    }
    __syncthreads();
    const int rn = t >> 2, ck = (t & 3) << 4;
    union { unsigned short u16[16]; uint4 q[2]; } pk;
#pragma unroll
    for (int e = 0; e < 16; ++e) pk.u16[e] = f2bf(T[rn][ck + e]);
    *(uint4*)&dst[(size_t)(n0 + rn) * DMODEL + k0 + ck]     = pk.q[0];
    *(uint4*)&dst[(size_t)(n0 + rn) * DMODEL + k0 + ck + 8] = pk.q[1];
}

// ============ bf16 MFMA GEMM ============
// OMODE 0: bf16 flat [m][n];  OMODE 1: bf16 V-transposed [B,H,Dk,S];  OMODE 2: f32 flat.
// Grid must be (8, 64): XCD-swizzled internally (nwg=512, bijective since 512%8==0).
template<int OMODE>
__device__ __forceinline__
void gemm_core(const unsigned short* __restrict__ A, const unsigned short* __restrict__ Bt,
               const float* __restrict__ bias, void* __restrict__ outv, const float scl)
{
    __shared__ __align__(16) char As[128 * 128];
    __shared__ __align__(16) char Bs[128 * 128];

    const int t  = threadIdx.x;
    const int l  = t & 63, w = t >> 6;
    const int g  = (l >> 4), lr = l & 15;
    const int wr = w >> 1, wc = w & 1;
    const int swz = (lr & 7) << 4;

    // XCD-aware swizzle (T1): each XCD gets 8 consecutive m-panels x all n-tiles.
    const int flat = (blockIdx.y << 3) | blockIdx.x;          // 0..511
    const int sid  = ((flat & 7) << 6) | (flat >> 3);
    const int m0 = (sid >> 3) << 7;
    const int n0 = (sid & 7) << 7;

    f32x4 acc[4][4];
#pragma unroll
    for (int i = 0; i < 4; ++i)
#pragma unroll
        for (int j = 0; j < 4; ++j) acc[i][j] = (f32x4){0.f, 0.f, 0.f, 0.f};

    for (int k0 = 0; k0 < DMODEL; k0 += 64) {
        __syncthreads();
#pragma unroll
        for (int qd = 0; qd < 4; ++qd) {
            const int o   = (t + qd * 256) << 4;
            const int row = o >> 7;
            const int c   = (o & 127) ^ ((row & 7) << 4);
            gload16((const char*)A  + (((size_t)(m0 + row) * DMODEL + k0) << 1) + c, As + o);
            gload16((const char*)Bt + (((size_t)(n0 + row) * DMODEL + k0) << 1) + c, Bs + o);
        }
        __syncthreads();

        short8 af[4][2], bf[4][2];
#pragma unroll
        for (int i = 0; i < 4; ++i)
#pragma unroll
            for (int kk = 0; kk < 2; ++kk) {
                const int off = (kk * 64 + g * 16) ^ swz;
                af[i][kk] = *(const short8*)(As + (wr * 64 + i * 16 + lr) * 128 + off);
                bf[i][kk] = *(const short8*)(Bs + (wc * 64 + i * 16 + lr) * 128 + off);
            }
        __builtin_amdgcn_s_setprio(1);
#pragma unroll
        for (int kk = 0; kk < 2; ++kk)
#pragma unroll
            for (int i = 0; i < 4; ++i)
#pragma unroll
                for (int j = 0; j < 4; ++j)
                    acc[i][j] = __builtin_amdgcn_mfma_f32_16x16x32_bf16(
                        af[i][kk], bf[j][kk], acc[i][j], 0, 0, 0);
        __builtin_amdgcn_s_setprio(0);
    }

    float bj[4];
#pragma unroll
    for (int j = 0; j < 4; ++j) bj[j] = bias[n0 + wc * 64 + j * 16 + lr];

#pragma unroll
    for (int i = 0; i < 4; ++i)
#pragma unroll
        for (int j = 0; j < 4; ++j) {
            const int mb = m0 + wr * 64 + i * 16 + g * 4;
            const int n  = n0 + wc * 64 + j * 16 + lr;
            float v[4];
#pragma unroll
            for (int r = 0; r < 4; ++r) v[r] = (acc[i][j][r] + bj[j]) * scl;
            if (OMODE == 0) {
                unsigned short* outp = (unsigned short*)outv;
#pragma unroll
                for (int r = 0; r < 4; ++r)
                    outp[(size_t)(mb + r) * DMODEL + n] = f2bf(v[r]);
            } else if (OMODE == 1) {
                unsigned short* outp = (unsigned short*)outv;
                const int b = mb >> 11, s = mb & (SEQLEN - 1);
                const size_t idx = (((size_t)(b * NHEADS + (n >> 6)) * DKDIM + (n & 63)) << 11) + s;
                uint2 pk;
                pk.x = (unsigned)f2bf(v[0]) | ((unsigned)f2bf(v[1]) << 16);
                pk.y = (unsigned)f2bf(v[2]) | ((unsigned)f2bf(v[3]) << 16);
                *(uint2*)&outp[idx] = pk;
            } else {
                float* outp = (float*)outv;
#pragma unroll
                for (int r = 0; r < 4; ++r)
                    outp[(size_t)(mb + r) * DMODEL + n] = v[r];
            }
        }
}

#define QSCALE 0.1803368801111137f   // 0.125 * log2(e): scores come out in log2 units

__global__ __launch_bounds__(256)
void qkv_gemm_kernel(const unsigned short* __restrict__ xb, const unsigned short* __restrict__ wt,
                     const float* __restrict__ bq, const float* __restrict__ bk,
                     const float* __restrict__ bv,
                     unsigned short* __restrict__ Qb, unsigned short* __restrict__ Kb,
                     unsigned short* __restrict__ Vt)
{
    if (blockIdx.z == 0)      gemm_core<0>(xb, wt,                      bq, Qb, QSCALE);
    else if (blockIdx.z == 1) gemm_core<0>(xb, wt + DMODEL * DMODEL,     bk, Kb, 1.0f);
    else                      gemm_core<1>(xb, wt + 2 * DMODEL * DMODEL, bv, Vt, 1.0f);
}

__global__ __launch_bounds__(256)
void out_gemm_kernel(const unsigned short* __restrict__ ctx, const unsigned short* __restrict__ wt,
                     const float* __restrict__ bo, float* __restrict__ out)
{
    gemm_core<2>(ctx, wt + 3 * DMODEL * DMODEL, bo, out, 1.0f);
}

// ============ bf16 MFMA flash attention (verified round-7 structure) ============
// 512 thr = 8 waves, 32 q/wave, KV tiles of 64, triple-buffered counted-vmcnt staging.
// (1) raw v_exp_f32 via __builtin_amdgcn_exp2f (no OCML wrapper),
// (2) lsum accumulated by ones-MFMA on the matrix pipe (no VALU adds/shfl),
// (3) half-split score state (16 regs) keeps the register granule at 4 waves/SIMD.
__device__ __forceinline__
void attn_body(const char* __restrict__ Kbuf, const char* __restrict__ Vbuf,
               const short8 (&qf)[4], const short8 ones,
               f32x16 (&po)[2], f32x16& po_l,
               int q32, int hi, int swz)
{
#pragma unroll
    for (int hf = 0; hf < 2; ++hf) {
        // ---- S^T for kv rows [32*hf, 32*hf+32) ----
        f32x16 s;
#pragma unroll
        for (int r = 0; r < 16; ++r) s[r] = 0.f;
        short8 kf[4];
#pragma unroll
        for (int kk = 0; kk < 4; ++kk)
            kf[kk] = *(const short8*)(Kbuf + (hf * 32 + q32) * 128 + ((kk * 32 + hi * 16) ^ swz));
        __builtin_amdgcn_s_setprio(1);
#pragma unroll
        for (int kk = 0; kk < 4; ++kk)
            s = __builtin_amdgcn_mfma_f32_32x32x16_bf16(kf[kk], qf[kk], s, 0, 0, 0);
        __builtin_amdgcn_s_setprio(0);

        // ---- p = 2^s, raw v_exp_f32 (scores bounded; flush-to-zero is correct) ----
#pragma unroll
        for (int r = 0; r < 16; ++r) s[r] = __builtin_amdgcn_exp2f(s[r]);

        // ---- build PV B-fragments in-register (T12): k-blocks 2hf, 2hf+1 ----
        short8 pf[2];
#pragma unroll
        for (int j = 0; j < 2; ++j) {
            const int bse = j * 8;
            unsigned wA0, wA1, wB0, wB1;
            asm("v_cvt_pk_bf16_f32 %0, %1, %2" : "=v"(wA0) : "v"(s[bse + 0]), "v"(s[bse + 1]));
            asm("v_cvt_pk_bf16_f32 %0, %1, %2" : "=v"(wA1) : "v"(s[bse + 2]), "v"(s[bse + 3]));
            asm("v_cvt_pk_bf16_f32 %0, %1, %2" : "=v"(wB0) : "v"(s[bse + 4]), "v"(s[bse + 5]));
            asm("v_cvt_pk_bf16_f32 %0, %1, %2" : "=v"(wB1) : "v"(s[bse + 6]), "v"(s[bse + 7]));
            asm volatile("v_permlane32_swap_b32 %0, %1" : "+v"(wA0), "+v"(wB0));
            asm volatile("v_permlane32_swap_b32 %0, %1" : "+v"(wA1), "+v"(wB1));
            union { unsigned u[4]; short8 s8; } pk;
            pk.u[0] = wA0; pk.u[1] = wA1; pk.u[2] = wB0; pk.u[3] = wB1;
            pf[j] = pk.s8;
        }

        // ---- PV + lsum-via-MFMA: ctx^T += Vt.P^T ; po_l += ones.P^T ----
        short8 vf0[2], vf1[2];
#pragma unroll
        for (int j = 0; j < 2; ++j) {
            const int ks = hf * 2 + j;
            vf0[j] = *(const short8*)(Vbuf + q32 * 128 + ((ks * 32 + hi * 16) ^ swz));
            vf1[j] = *(const short8*)(Vbuf + (32 + q32) * 128 + ((ks * 32 + hi * 16) ^ swz));
        }
        __builtin_amdgcn_s_setprio(1);
#pragma unroll
        for (int j = 0; j < 2; ++j) {
            po[0] = __builtin_amdgcn_mfma_f32_32x32x16_bf16(vf0[j], pf[j], po[0], 0, 0, 0);
            po[1] = __builtin_amdgcn_mfma_f32_32x32x16_bf16(vf1[j], pf[j], po[1], 0, 0, 0);
            po_l  = __builtin_amdgcn_mfma_f32_32x32x16_bf16(ones,   pf[j], po_l,  0, 0, 0);
        }
        __builtin_amdgcn_s_setprio(0);
    }
}

__global__ __launch_bounds__(512)
void attn_kernel(const unsigned short* __restrict__ Qb, const unsigned short* __restrict__ Kb,
                 const unsigned short* __restrict__ Vt, unsigned short* __restrict__ ctx)
{
    __shared__ __align__(16) char smem[49152];   // K bufs [0,24K) x3, V bufs [24K,48K) x3

    const int t   = threadIdx.x;
    const int l   = t & 63, w = t >> 6;
    const int q32 = l & 31, hi = l >> 5;
    const int swz = (q32 & 7) << 4;

    // XCD-aware swizzle (T1): each XCD gets 8 complete heads (K/V = 4MB = L2-resident).
    const int flat = (blockIdx.y << 3) | blockIdx.x;          // 0..511
    const int sid  = ((flat & 7) << 6) | (flat >> 3);
    const int qt = sid & 7;
    const int bh = sid >> 3;
    const int b  = bh >> 4, h = bh & 15;
    const int coln = h * DKDIM;

    const size_t qrow  = (size_t)b * SEQLEN + qt * 256 + w * 32 + q32;
    const size_t krow0 = (size_t)b * SEQLEN;
    const size_t vbase = (size_t)(b * NHEADS + h) * DKDIM * SEQLEN;

    // Q fragments in registers (pre-scaled by 0.125*log2e in projection)
    short8 qf[4];
#pragma unroll
    for (int kk = 0; kk < 4; ++kk)
        qf[kk] = *(const short8*)(Qb + qrow * DMODEL + coln + kk * 16 + hi * 8);

    short8 ones;
#pragma unroll
    for (int e = 0; e < 8; ++e) ones[e] = (short)0x3F80;   // bf16 1.0

    f32x16 po[2], po_l;
#pragma unroll
    for (int r = 0; r < 16; ++r) { po[0][r] = 0.f; po[1][r] = 0.f; po_l[r] = 0.f; }

    const int so   = t << 4;             // staging offset, 0..8191
    const int srow = so >> 7;
    const int sc_  = (so & 127) ^ ((srow & 7) << 4);

#define STAGE(bufidx, kt)                                                                    \
    do {                                                                                     \
        gload16((const char*)Kb + (((krow0 + (kt) * 64 + srow) * DMODEL + coln) << 1) + sc_, \
                smem + (bufidx) * 8192 + so);                                                \
        gload16((const char*)Vt + ((vbase + (size_t)srow * SEQLEN + (kt) * 64) << 1) + sc_,  \
                smem + 24576 + (bufidx) * 8192 + so);                                        \
    } while (0)

    STAGE(0, 0);
    STAGE(1, 1);

#pragma unroll 1
    for (int kt = 0; kt < 31; ++kt) {
        // own stage(kt) verified; stage(kt+1)'s 2 loads stay in flight across barrier
        asm volatile("s_waitcnt vmcnt(2)" ::: "memory");
        __builtin_amdgcn_s_barrier();
        if (kt + 2 < 32) STAGE((kt + 2) % 3, kt + 2);
        const int buf = kt % 3;
        attn_body(smem + buf * 8192, smem + 24576 + buf * 8192,
                  qf, ones, po, po_l, q32, hi, swz);
    }
    // tail: tile 31 (buf 1)
    asm volatile("s_waitcnt vmcnt(0)" ::: "memory");
    __builtin_amdgcn_s_barrier();
    attn_body(smem + 8192, smem + 24576 + 8192, qf, ones, po, po_l, q32, hi, swz);

    __syncthreads();                      // before smem reuse in epilogue

    // ---- epilogue: normalize (lsum = po_l, all rows equal), transpose, write ----
    const float inv = 1.0f / po_l[0];
    char* T = smem + w * 4096;            // per-wave [32 q][64 d] bf16, swizzled
#pragma unroll
    for (int i = 0; i < 2; ++i)
#pragma unroll
        for (int g4 = 0; g4 < 4; ++g4) {
            const int d0 = i * 32 + g4 * 8 + hi * 4;
            uint2 pk;
            pk.x = (unsigned)f2bf(po[i][g4 * 4 + 0] * inv) | ((unsigned)f2bf(po[i][g4 * 4 + 1] * inv) << 16);
            pk.y = (unsigned)f2bf(po[i][g4 * 4 + 2] * inv) | ((unsigned)f2bf(po[i][g4 * 4 + 3] * inv) << 16);
            *(uint2*)(T + ((q32 * 128 + d0 * 2) ^ swz)) = pk;
        }
    __syncthreads();
#pragma unroll
    for (int pass = 0; pass < 4; ++pass) {
        const int o   = (l + pass * 64) << 4;    // 0..4095
        const int row = o >> 7;
        const int c   = o & 127;
        const uint4 val = *(const uint4*)(T + (o ^ ((row & 7) << 4)));
        const size_t token = (size_t)b * SEQLEN + qt * 256 + w * 32 + row;
        *(uint4*)&ctx[token * DMODEL + coln + (c >> 1)] = val;
    }
#undef STAGE
}

extern "C" void kernel_launch(void* const* d_in, const int* in_sizes, int n_in,
                              void* d_out, int out_size, void* d_ws, size_t ws_size,
                              hipStream_t stream)
{
    const float* x  = (const float*)d_in[0];
    const float* Wq = (const float*)d_in[1];
    const float* bq = (const float*)d_in[2];
    const float* Wk = (const float*)d_in[3];
    const float* bk = (const float*)d_in[4];
    const float* Wv = (const float*)d_in[5];
    const float* bv = (const float*)d_in[6];
    const float* Wo = (const float*)d_in[7];
    const float* bo = (const float*)d_in[8];
    float* out = (float*)d_out;

    const size_t NE = (size_t)MTOT * DMODEL;
    unsigned short* xb  = (unsigned short*)d_ws;
    unsigned short* wt  = xb  + NE;
    unsigned short* Qb  = wt  + (size_t)4 * DMODEL * DMODEL;
    unsigned short* Kb  = Qb  + NE;
    unsigned short* Vt  = Kb  + NE;
    unsigned short* ctx = Vt  + NE;

    convert_x_kernel<<<dim3(NE / (256 * 8)), 256, 0, stream>>>(x, xb);
    convert_w_kernel<<<dim3(16, 16, 4), 256, 0, stream>>>(Wq, Wk, Wv, Wo, wt);
    qkv_gemm_kernel<<<dim3(8, 64, 3), 256, 0, stream>>>(xb, wt, bq, bk, bv, Qb, Kb, Vt);
    attn_kernel<<<dim3(SEQLEN / 256, NBATCH * NHEADS), dim3(512), 0, stream>>>(Qb, Kb, Vt, ctx);
    out_gemm_kernel<<<dim3(8, 64), 256, 0, stream>>>(ctx, wt, bo, out);
}

// Round 13
// 176.821 us; speedup vs baseline: 2.1920x; 1.0085x over previous
//
#include <hip/hip_runtime.h>
#include <math.h>

#define DMODEL 1024
#define NHEADS 16
#define DKDIM  64
#define SEQLEN 2048
#define NBATCH 4
#define MTOT   (NBATCH * SEQLEN)   // 8192

// NOTE (rounds 8-11 dead end): a pf-carried cross-body pipeline (PV(t-1) overlapping
// exp(t)) failed bit-identically (absmax 5.14e-2) under three different sync schemes,
// including plain __syncthreads quad-buffering. Cause never identified; structure
// abandoned. This file keeps the verified round-7/12 structure: PV in-body,
// triple-buffer, vmcnt(2) counted staging. Round-13 changes are issue-count-only:
// persistent-zero MFMA C-in (kills 32 v_mov/body) and x3 loop unroll (compile-time
// buffer offsets) - the wait/barrier/stage sequence is byte-identical to round 12.

typedef __attribute__((ext_vector_type(8)))  short short8;
typedef __attribute__((ext_vector_type(4)))  float f32x4;
typedef __attribute__((ext_vector_type(16))) float f32x16;

__device__ __forceinline__ unsigned short f2bf(float x) {
    unsigned u = __builtin_bit_cast(unsigned, x);
    unsigned r = (u + 0x7fffu + ((u >> 16) & 1u)) >> 16;
    return (unsigned short)r;
}

__device__ __forceinline__ void gload16(const void* g, void* l) {
    __builtin_amdgcn_global_load_lds(
        (const __attribute__((address_space(1))) void*)g,
        (__attribute__((address_space(3))) void*)l, 16, 0, 0);
}

// ============ convert x (f32 -> bf16 flat) ============
__global__ __launch_bounds__(256)
void convert_x_kernel(const float* __restrict__ x, unsigned short* __restrict__ xb)
{
    const size_t i = ((size_t)blockIdx.x * 256 + threadIdx.x) * 8;
    const float4 a = *(const float4*)&x[i];
    const float4 b = *(const float4*)&x[i + 4];
    union { unsigned short u[8]; uint4 q; } p;
    p.u[0] = f2bf(a.x); p.u[1] = f2bf(a.y); p.u[2] = f2bf(a.z); p.u[3] = f2bf(a.w);
    p.u[4] = f2bf(b.x); p.u[5] = f2bf(b.y); p.u[6] = f2bf(b.z); p.u[7] = f2bf(b.w);
    *(uint4*)&xb[i] = p.q;
}

// ============ convert + transpose W: W[k][n] f32 -> Wt[n][k] bf16 ============
__global__ __launch_bounds__(256)
void convert_w_kernel(const float* __restrict__ W0, const float* __restrict__ W1,
                      const float* __restrict__ W2, const float* __restrict__ W3,
                      unsigned short* __restrict__ wt)
{
    const int z = blockIdx.z;
    const float* W = (z == 0) ? W0 : (z == 1) ? W1 : (z == 2) ? W2 : W3;
    unsigned short* dst = wt + (size_t)z * DMODEL * DMODEL;
    const int n0 = blockIdx.x * 64, k0 = blockIdx.y * 64;
    __shared__ float T[64][65];
    const int t = threadIdx.x;
    const int r0 = t >> 4, c0 = (t & 15) << 2;
#pragma unroll
    for (int u = 0; u < 4; ++u) {
        const float4 wv = *(const float4*)&W[(size_t)(k0 + r0 + u * 16) * DMODEL + n0 + c0];
        T[c0 + 0][r0 + u * 16] = wv.x;
        T[c0 + 1][r0 + u * 16] = wv.y;
        T[c0 + 2][r0 + u * 16] = wv.z;
        T[c0 + 3][r0 + u * 16] = wv.w;
    }
    __syncthreads();
    const int rn = t >> 2, ck = (t & 3) << 4;
    union { unsigned short u16[16]; uint4 q[2]; } pk;
#pragma unroll
    for (int e = 0; e < 16; ++e) pk.u16[e] = f2bf(T[rn][ck + e]);
    *(uint4*)&dst[(size_t)(n0 + rn) * DMODEL + k0 + ck]     = pk.q[0];
    *(uint4*)&dst[(size_t)(n0 + rn) * DMODEL + k0 + ck + 8] = pk.q[1];
}

// ============ bf16 MFMA GEMM ============
// OMODE 0: bf16 flat [m][n];  OMODE 1: bf16 V-transposed [B,H,Dk,S];  OMODE 2: f32 flat.
// Grid must be (8, 64): XCD-swizzled internally (nwg=512, bijective since 512%8==0).
template<int OMODE>
__device__ __forceinline__
void gemm_core(const unsigned short* __restrict__ A, const unsigned short* __restrict__ Bt,
               const float* __restrict__ bias, void* __restrict__ outv, const float scl)
{
    __shared__ __align__(16) char As[128 * 128];
    __shared__ __align__(16) char Bs[128 * 128];

    const int t  = threadIdx.x;
    const int l  = t & 63, w = t >> 6;
    const int g  = (l >> 4), lr = l & 15;
    const int wr = w >> 1, wc = w & 1;
    const int swz = (lr & 7) << 4;

    // XCD-aware swizzle (T1): each XCD gets 8 consecutive m-panels x all n-tiles.
    const int flat = (blockIdx.y << 3) | blockIdx.x;          // 0..511
    const int sid  = ((flat & 7) << 6) | (flat >> 3);
    const int m0 = (sid >> 3) << 7;
    const int n0 = (sid & 7) << 7;

    f32x4 acc[4][4];
#pragma unroll
    for (int i = 0; i < 4; ++i)
#pragma unroll
        for (int j = 0; j < 4; ++j) acc[i][j] = (f32x4){0.f, 0.f, 0.f, 0.f};

    for (int k0 = 0; k0 < DMODEL; k0 += 64) {
        __syncthreads();
#pragma unroll
        for (int qd = 0; qd < 4; ++qd) {
            const int o   = (t + qd * 256) << 4;
            const int row = o >> 7;
            const int c   = (o & 127) ^ ((row & 7) << 4);
            gload16((const char*)A  + (((size_t)(m0 + row) * DMODEL + k0) << 1) + c, As + o);
            gload16((const char*)Bt + (((size_t)(n0 + row) * DMODEL + k0) << 1) + c, Bs + o);
        }
        __syncthreads();

        short8 af[4][2], bf[4][2];
#pragma unroll
        for (int i = 0; i < 4; ++i)
#pragma unroll
            for (int kk = 0; kk < 2; ++kk) {
                const int off = (kk * 64 + g * 16) ^ swz;
                af[i][kk] = *(const short8*)(As + (wr * 64 + i * 16 + lr) * 128 + off);
                bf[i][kk] = *(const short8*)(Bs + (wc * 64 + i * 16 + lr) * 128 + off);
            }
        __builtin_amdgcn_s_setprio(1);
#pragma unroll
        for (int kk = 0; kk < 2; ++kk)
#pragma unroll
            for (int i = 0; i < 4; ++i)
#pragma unroll
                for (int j = 0; j < 4; ++j)
                    acc[i][j] = __builtin_amdgcn_mfma_f32_16x16x32_bf16(
                        af[i][kk], bf[j][kk], acc[i][j], 0, 0, 0);
        __builtin_amdgcn_s_setprio(0);
    }

    float bj[4];
#pragma unroll
    for (int j = 0; j < 4; ++j) bj[j] = bias[n0 + wc * 64 + j * 16 + lr];

#pragma unroll
    for (int i = 0; i < 4; ++i)
#pragma unroll
        for (int j = 0; j < 4; ++j) {
            const int mb = m0 + wr * 64 + i * 16 + g * 4;
            const int n  = n0 + wc * 64 + j * 16 + lr;
            float v[4];
#pragma unroll
            for (int r = 0; r < 4; ++r) v[r] = (acc[i][j][r] + bj[j]) * scl;
            if (OMODE == 0) {
                unsigned short* outp = (unsigned short*)outv;
#pragma unroll
                for (int r = 0; r < 4; ++r)
                    outp[(size_t)(mb + r) * DMODEL + n] = f2bf(v[r]);
            } else if (OMODE == 1) {
                unsigned short* outp = (unsigned short*)outv;
                const int b = mb >> 11, s = mb & (SEQLEN - 1);
                const size_t idx = (((size_t)(b * NHEADS + (n >> 6)) * DKDIM + (n & 63)) << 11) + s;
                uint2 pk;
                pk.x = (unsigned)f2bf(v[0]) | ((unsigned)f2bf(v[1]) << 16);
                pk.y = (unsigned)f2bf(v[2]) | ((unsigned)f2bf(v[3]) << 16);
                *(uint2*)&outp[idx] = pk;
            } else {
                float* outp = (float*)outv;
#pragma unroll
                for (int r = 0; r < 4; ++r)
                    outp[(size_t)(mb + r) * DMODEL + n] = v[r];
            }
        }
}

#define QSCALE 0.1803368801111137f   // 0.125 * log2(e): scores come out in log2 units

__global__ __launch_bounds__(256)
void qkv_gemm_kernel(const unsigned short* __restrict__ xb, const unsigned short* __restrict__ wt,
                     const float* __restrict__ bq, const float* __restrict__ bk,
                     const float* __restrict__ bv,
                     unsigned short* __restrict__ Qb, unsigned short* __restrict__ Kb,
                     unsigned short* __restrict__ Vt)
{
    if (blockIdx.z == 0)      gemm_core<0>(xb, wt,                      bq, Qb, QSCALE);
    else if (blockIdx.z == 1) gemm_core<0>(xb, wt + DMODEL * DMODEL,     bk, Kb, 1.0f);
    else                      gemm_core<1>(xb, wt + 2 * DMODEL * DMODEL, bv, Vt, 1.0f);
}

__global__ __launch_bounds__(256)
void out_gemm_kernel(const unsigned short* __restrict__ ctx, const unsigned short* __restrict__ wt,
                     const float* __restrict__ bo, float* __restrict__ out)
{
    gemm_core<2>(ctx, wt + 3 * DMODEL * DMODEL, bo, out, 1.0f);
}

// ============ bf16 MFMA flash attention (round-7 structure, issue-slimmed) ============
// 512 thr = 8 waves, 32 q/wave, KV tiles of 64, triple-buffered counted-vmcnt staging.
// (1) raw v_exp_f32 via __builtin_amdgcn_exp2f, (2) lsum via ones-MFMA,
// (3) persistent zero C-in block z16 (no per-body v_mov zero-init),
// (4) x3-unrolled main loop: all buffer offsets compile-time.
__device__ __forceinline__
void attn_body(const char* __restrict__ Kbuf, const char* __restrict__ Vbuf,
               const short8 (&qf)[4], const short8 ones, const f32x16& z16,
               f32x16 (&po)[2], f32x16& po_l,
               int q32, int hi, int swz)
{
#pragma unroll
    for (int hf = 0; hf < 2; ++hf) {
        // ---- S^T for kv rows [32*hf, 32*hf+32) ----
        short8 kf[4];
#pragma unroll
        for (int kk = 0; kk < 4; ++kk)
            kf[kk] = *(const short8*)(Kbuf + (hf * 32 + q32) * 128 + ((kk * 32 + hi * 16) ^ swz));
        __builtin_amdgcn_s_setprio(1);
        f32x16 s = __builtin_amdgcn_mfma_f32_32x32x16_bf16(kf[0], qf[0], z16, 0, 0, 0);
#pragma unroll
        for (int kk = 1; kk < 4; ++kk)
            s = __builtin_amdgcn_mfma_f32_32x32x16_bf16(kf[kk], qf[kk], s, 0, 0, 0);
        __builtin_amdgcn_s_setprio(0);

        // ---- p = 2^s, raw v_exp_f32 (scores bounded; flush-to-zero is correct) ----
#pragma unroll
        for (int r = 0; r < 16; ++r) s[r] = __builtin_amdgcn_exp2f(s[r]);

        // ---- build PV B-fragments in-register (T12): k-blocks 2hf, 2hf+1 ----
        short8 pf[2];
#pragma unroll
        for (int j = 0; j < 2; ++j) {
            const int bse = j * 8;
            unsigned wA0, wA1, wB0, wB1;
            asm("v_cvt_pk_bf16_f32 %0, %1, %2" : "=v"(wA0) : "v"(s[bse + 0]), "v"(s[bse + 1]));
            asm("v_cvt_pk_bf16_f32 %0, %1, %2" : "=v"(wA1) : "v"(s[bse + 2]), "v"(s[bse + 3]));
            asm("v_cvt_pk_bf16_f32 %0, %1, %2" : "=v"(wB0) : "v"(s[bse + 4]), "v"(s[bse + 5]));
            asm("v_cvt_pk_bf16_f32 %0, %1, %2" : "=v"(wB1) : "v"(s[bse + 6]), "v"(s[bse + 7]));
            asm volatile("v_permlane32_swap_b32 %0, %1" : "+v"(wA0), "+v"(wB0));
            asm volatile("v_permlane32_swap_b32 %0, %1" : "+v"(wA1), "+v"(wB1));
            union { unsigned u[4]; short8 s8; } pk;
            pk.u[0] = wA0; pk.u[1] = wA1; pk.u[2] = wB0; pk.u[3] = wB1;
            pf[j] = pk.s8;
        }

        // ---- PV + lsum-via-MFMA: ctx^T += Vt.P^T ; po_l += ones.P^T ----
        short8 vf0[2], vf1[2];
#pragma unroll
        for (int j = 0; j < 2; ++j) {
            const int ks = hf * 2 + j;
            vf0[j] = *(const short8*)(Vbuf + q32 * 128 + ((ks * 32 + hi * 16) ^ swz));
            vf1[j] = *(const short8*)(Vbuf + (32 + q32) * 128 + ((ks * 32 + hi * 16) ^ swz));
        }
        __builtin_amdgcn_s_setprio(1);
#pragma unroll
        for (int j = 0; j < 2; ++j) {
            po[0] = __builtin_amdgcn_mfma_f32_32x32x16_bf16(vf0[j], pf[j], po[0], 0, 0, 0);
            po[1] = __builtin_amdgcn_mfma_f32_32x32x16_bf16(vf1[j], pf[j], po[1], 0, 0, 0);
            po_l  = __builtin_amdgcn_mfma_f32_32x32x16_bf16(ones,   pf[j], po_l,  0, 0, 0);
        }
        __builtin_amdgcn_s_setprio(0);
    }
}

__global__ __launch_bounds__(512)
void attn_kernel(const unsigned short* __restrict__ Qb, const unsigned short* __restrict__ Kb,
                 const unsigned short* __restrict__ Vt, unsigned short* __restrict__ ctx)
{
    __shared__ __align__(16) char smem[49152];   // K bufs [0,24K) x3, V bufs [24K,48K) x3

    const int t   = threadIdx.x;
    const int l   = t & 63, w = t >> 6;
    const int q32 = l & 31, hi = l >> 5;
    const int swz = (q32 & 7) << 4;

    // XCD-aware swizzle (T1): each XCD gets 8 complete heads (K/V = 4MB = L2-resident).
    const int flat = (blockIdx.y << 3) | blockIdx.x;          // 0..511
    const int sid  = ((flat & 7) << 6) | (flat >> 3);
    const int qt = sid & 7;
    const int bh = sid >> 3;
    const int b  = bh >> 4, h = bh & 15;
    const int coln = h * DKDIM;

    const size_t qrow  = (size_t)b * SEQLEN + qt * 256 + w * 32 + q32;
    const size_t krow0 = (size_t)b * SEQLEN;
    const size_t vbase = (size_t)(b * NHEADS + h) * DKDIM * SEQLEN;

    // Q fragments in registers (pre-scaled by 0.125*log2e in projection)
    short8 qf[4];
#pragma unroll
    for (int kk = 0; kk < 4; ++kk)
        qf[kk] = *(const short8*)(Qb + qrow * DMODEL + coln + kk * 16 + hi * 8);

    short8 ones;
#pragma unroll
    for (int e = 0; e < 8; ++e) ones[e] = (short)0x3F80;   // bf16 1.0

    // persistent zero C-in block (pins 16 VGPRs; occupancy is grid/LDS-limited, so free)
    f32x16 z16;
#pragma unroll
    for (int r = 0; r < 16; ++r) z16[r] = 0.f;

    f32x16 po[2], po_l;
#pragma unroll
    for (int r = 0; r < 16; ++r) { po[0][r] = 0.f; po[1][r] = 0.f; po_l[r] = 0.f; }

    const int so   = t << 4;             // staging offset, 0..8191
    const int srow = so >> 7;
    const int sc_  = (so & 127) ^ ((srow & 7) << 4);

#define STAGE(bufidx, kt)                                                                    \
    do {                                                                                     \
        gload16((const char*)Kb + (((krow0 + (kt) * 64 + srow) * DMODEL + coln) << 1) + sc_, \
                smem + (bufidx) * 8192 + so);                                                \
        gload16((const char*)Vt + ((vbase + (size_t)srow * SEQLEN + (kt) * 64) << 1) + sc_,  \
                smem + 24576 + (bufidx) * 8192 + so);                                        \
    } while (0)
#define BODY(bufidx)                                                            \
    attn_body(smem + (bufidx) * 8192, smem + 24576 + (bufidx) * 8192,           \
              qf, ones, z16, po, po_l, q32, hi, swz)

    STAGE(0, 0);
    STAGE(1, 1);

    // bodies 0..29: x3 unrolled, buffer indices compile-time. Same wait/barrier/stage
    // sequence as round 12 (body t: vmcnt(2); barrier; stage t+2; compute buf t%3).
#pragma unroll 1
    for (int kt = 0; kt < 30; kt += 3) {
        asm volatile("s_waitcnt vmcnt(2)" ::: "memory");
        __builtin_amdgcn_s_barrier();
        STAGE(2, kt + 2);
        BODY(0);

        asm volatile("s_waitcnt vmcnt(2)" ::: "memory");
        __builtin_amdgcn_s_barrier();
        STAGE(0, kt + 3);
        BODY(1);

        asm volatile("s_waitcnt vmcnt(2)" ::: "memory");
        __builtin_amdgcn_s_barrier();
        STAGE(1, kt + 4);
        BODY(2);
    }

    // tail: body 30 (buf 0; stage(31) still in flight), body 31 (buf 1; drain)
    asm volatile("s_waitcnt vmcnt(2)" ::: "memory");
    __builtin_amdgcn_s_barrier();
    BODY(0);
    asm volatile("s_waitcnt vmcnt(0)" ::: "memory");
    __builtin_amdgcn_s_barrier();
    BODY(1);

    __syncthreads();                      // before smem reuse in epilogue

    // ---- epilogue: normalize (lsum = po_l, all rows equal), transpose, write ----
    const float inv = 1.0f / po_l[0];
    char* T = smem + w * 4096;            // per-wave [32 q][64 d] bf16, swizzled
#pragma unroll
    for (int i = 0; i < 2; ++i)
#pragma unroll
        for (int g4 = 0; g4 < 4; ++g4) {
            const int d0 = i * 32 + g4 * 8 + hi * 4;
            uint2 pk;
            pk.x = (unsigned)f2bf(po[i][g4 * 4 + 0] * inv) | ((unsigned)f2bf(po[i][g4 * 4 + 1] * inv) << 16);
            pk.y = (unsigned)f2bf(po[i][g4 * 4 + 2] * inv) | ((unsigned)f2bf(po[i][g4 * 4 + 3] * inv) << 16);
            *(uint2*)(T + ((q32 * 128 + d0 * 2) ^ swz)) = pk;
        }
    __syncthreads();
#pragma unroll
    for (int pass = 0; pass < 4; ++pass) {
        const int o   = (l + pass * 64) << 4;    // 0..4095
        const int row = o >> 7;
        const int c   = o & 127;
        const uint4 val = *(const uint4*)(T + (o ^ ((row & 7) << 4)));
        const size_t token = (size_t)b * SEQLEN + qt * 256 + w * 32 + row;
        *(uint4*)&ctx[token * DMODEL + coln + (c >> 1)] = val;
    }
#undef STAGE
#undef BODY
}

extern "C" void kernel_launch(void* const* d_in, const int* in_sizes, int n_in,
                              void* d_out, int out_size, void* d_ws, size_t ws_size,
                              hipStream_t stream)
{
    const float* x  = (const float*)d_in[0];
    const float* Wq = (const float*)d_in[1];
    const float* bq = (const float*)d_in[2];
    const float* Wk = (const float*)d_in[3];
    const float* bk = (const float*)d_in[4];
    const float* Wv = (const float*)d_in[5];
    const float* bv = (const float*)d_in[6];
    const float* Wo = (const float*)d_in[7];
    const float* bo = (const float*)d_in[8];
    float* out = (float*)d_out;

    const size_t NE = (size_t)MTOT * DMODEL;
    unsigned short* xb  = (unsigned short*)d_ws;
    unsigned short* wt  = xb  + NE;
    unsigned short* Qb  = wt  + (size_t)4 * DMODEL * DMODEL;
    unsigned short* Kb  = Qb  + NE;
    unsigned short* Vt  = Kb  + NE;
    unsigned short* ctx = Vt  + NE;

    convert_x_kernel<<<dim3(NE / (256 * 8)), 256, 0, stream>>>(x, xb);
    convert_w_kernel<<<dim3(16, 16, 4), 256, 0, stream>>>(Wq, Wk, Wv, Wo, wt);
    qkv_gemm_kernel<<<dim3(8, 64, 3), 256, 0, stream>>>(xb, wt, bq, bk, bv, Qb, Kb, Vt);
    attn_kernel<<<dim3(SEQLEN / 256, NBATCH * NHEADS), dim3(512), 0, stream>>>(Qb, Kb, Vt, ctx);
    out_gemm_kernel<<<dim3(8, 64), 256, 0, stream>>>(ctx, wt, bo, out);
}

// Round 14
// 175.847 us; speedup vs baseline: 2.2041x; 1.0055x over previous
//
#include <hip/hip_runtime.h>
#include <math.h>

#define DMODEL 1024
#define NHEADS 16
#define DKDIM  64
#define SEQLEN 2048
#define NBATCH 4
#define MTOT   (NBATCH * SEQLEN)   // 8192

// NOTE (rounds 8-11 dead end): pf-carried cross-body pipeline failed bit-identically
// under three sync schemes; abandoned. Attention keeps the verified in-body compute
// (r7/r13) on the verified round-5 double-buffer __syncthreads loop, with KV=128
// tiles (16 iterations, half the barriers of KV=64).

typedef __attribute__((ext_vector_type(8)))  short short8;
typedef __attribute__((ext_vector_type(4)))  float f32x4;
typedef __attribute__((ext_vector_type(16))) float f32x16;

__device__ __forceinline__ unsigned short f2bf(float x) {
    unsigned u = __builtin_bit_cast(unsigned, x);
    unsigned r = (u + 0x7fffu + ((u >> 16) & 1u)) >> 16;
    return (unsigned short)r;
}

__device__ __forceinline__ void gload16(const void* g, void* l) {
    __builtin_amdgcn_global_load_lds(
        (const __attribute__((address_space(1))) void*)g,
        (__attribute__((address_space(3))) void*)l, 16, 0, 0);
}

// ============ merged convert: x (f32->bf16) + W (f32->bf16 transposed) ============
// grid.x = 4096 + 1024. Blocks [0,4096): x chunks. Blocks [4096,5120): W 64x64 tiles
// (wid>>8 = which W, (wid>>4)&15 = n-tile, wid&15 = k-tile).
__global__ __launch_bounds__(256)
void convert_all_kernel(const float* __restrict__ x,
                        const float* __restrict__ W0, const float* __restrict__ W1,
                        const float* __restrict__ W2, const float* __restrict__ W3,
                        unsigned short* __restrict__ xb, unsigned short* __restrict__ wt)
{
    const int bid = blockIdx.x;
    const int t = threadIdx.x;
    if (bid < 4096) {
        const size_t i = ((size_t)bid * 256 + t) * 8;
        const float4 a = *(const float4*)&x[i];
        const float4 b = *(const float4*)&x[i + 4];
        union { unsigned short u[8]; uint4 q; } p;
        p.u[0] = f2bf(a.x); p.u[1] = f2bf(a.y); p.u[2] = f2bf(a.z); p.u[3] = f2bf(a.w);
        p.u[4] = f2bf(b.x); p.u[5] = f2bf(b.y); p.u[6] = f2bf(b.z); p.u[7] = f2bf(b.w);
        *(uint4*)&xb[i] = p.q;
        return;
    }
    const int wid = bid - 4096;
    const int z  = wid >> 8;
    const float* W = (z == 0) ? W0 : (z == 1) ? W1 : (z == 2) ? W2 : W3;
    unsigned short* dst = wt + (size_t)z * DMODEL * DMODEL;
    const int n0 = ((wid >> 4) & 15) * 64, k0 = (wid & 15) * 64;
    __shared__ float T[64][65];
    const int r0 = t >> 4, c0 = (t & 15) << 2;
#pragma unroll
    for (int u = 0; u < 4; ++u) {
        const float4 wv = *(const float4*)&W[(size_t)(k0 + r0 + u * 16) * DMODEL + n0 + c0];
        T[c0 + 0][r0 + u * 16] = wv.x;
        T[c0 + 1][r0 + u * 16] = wv.y;
        T[c0 + 2][r0 + u * 16] = wv.z;
        T[c0 + 3][r0 + u * 16] = wv.w;
    }
    __syncthreads();
    const int rn = t >> 2, ck = (t & 3) << 4;
    union { unsigned short u16[16]; uint4 q[2]; } pk;
#pragma unroll
    for (int e = 0; e < 16; ++e) pk.u16[e] = f2bf(T[rn][ck + e]);
    *(uint4*)&dst[(size_t)(n0 + rn) * DMODEL + k0 + ck]     = pk.q[0];
    *(uint4*)&dst[(size_t)(n0 + rn) * DMODEL + k0 + ck + 8] = pk.q[1];
}

// ============ bf16 MFMA GEMM ============
// OMODE 0: bf16 flat [m][n];  OMODE 1: bf16 V-transposed [B,H,Dk,S];  OMODE 2: f32 flat.
// Grid must be (8, 64): XCD-swizzled internally (nwg=512, bijective since 512%8==0).
template<int OMODE>
__device__ __forceinline__
void gemm_core(const unsigned short* __restrict__ A, const unsigned short* __restrict__ Bt,
               const float* __restrict__ bias, void* __restrict__ outv, const float scl)
{
    __shared__ __align__(16) char As[128 * 128];
    __shared__ __align__(16) char Bs[128 * 128];

    const int t  = threadIdx.x;
    const int l  = t & 63, w = t >> 6;
    const int g  = (l >> 4), lr = l & 15;
    const int wr = w >> 1, wc = w & 1;
    const int swz = (lr & 7) << 4;

    // XCD-aware swizzle (T1): each XCD gets 8 consecutive m-panels x all n-tiles.
    const int flat = (blockIdx.y << 3) | blockIdx.x;          // 0..511
    const int sid  = ((flat & 7) << 6) | (flat >> 3);
    const int m0 = (sid >> 3) << 7;
    const int n0 = (sid & 7) << 7;

    f32x4 acc[4][4];
#pragma unroll
    for (int i = 0; i < 4; ++i)
#pragma unroll
        for (int j = 0; j < 4; ++j) acc[i][j] = (f32x4){0.f, 0.f, 0.f, 0.f};

    for (int k0 = 0; k0 < DMODEL; k0 += 64) {
        __syncthreads();
#pragma unroll
        for (int qd = 0; qd < 4; ++qd) {
            const int o   = (t + qd * 256) << 4;
            const int row = o >> 7;
            const int c   = (o & 127) ^ ((row & 7) << 4);
            gload16((const char*)A  + (((size_t)(m0 + row) * DMODEL + k0) << 1) + c, As + o);
            gload16((const char*)Bt + (((size_t)(n0 + row) * DMODEL + k0) << 1) + c, Bs + o);
        }
        __syncthreads();

        short8 af[4][2], bf[4][2];
#pragma unroll
        for (int i = 0; i < 4; ++i)
#pragma unroll
            for (int kk = 0; kk < 2; ++kk) {
                const int off = (kk * 64 + g * 16) ^ swz;
                af[i][kk] = *(const short8*)(As + (wr * 64 + i * 16 + lr) * 128 + off);
                bf[i][kk] = *(const short8*)(Bs + (wc * 64 + i * 16 + lr) * 128 + off);
            }
        __builtin_amdgcn_s_setprio(1);
#pragma unroll
        for (int kk = 0; kk < 2; ++kk)
#pragma unroll
            for (int i = 0; i < 4; ++i)
#pragma unroll
                for (int j = 0; j < 4; ++j)
                    acc[i][j] = __builtin_amdgcn_mfma_f32_16x16x32_bf16(
                        af[i][kk], bf[j][kk], acc[i][j], 0, 0, 0);
        __builtin_amdgcn_s_setprio(0);
    }

    float bj[4];
#pragma unroll
    for (int j = 0; j < 4; ++j) bj[j] = bias[n0 + wc * 64 + j * 16 + lr];

#pragma unroll
    for (int i = 0; i < 4; ++i)
#pragma unroll
        for (int j = 0; j < 4; ++j) {
            const int mb = m0 + wr * 64 + i * 16 + g * 4;
            const int n  = n0 + wc * 64 + j * 16 + lr;
            float v[4];
#pragma unroll
            for (int r = 0; r < 4; ++r) v[r] = (acc[i][j][r] + bj[j]) * scl;
            if (OMODE == 0) {
                unsigned short* outp = (unsigned short*)outv;
#pragma unroll
                for (int r = 0; r < 4; ++r)
                    outp[(size_t)(mb + r) * DMODEL + n] = f2bf(v[r]);
            } else if (OMODE == 1) {
                unsigned short* outp = (unsigned short*)outv;
                const int b = mb >> 11, s = mb & (SEQLEN - 1);
                const size_t idx = (((size_t)(b * NHEADS + (n >> 6)) * DKDIM + (n & 63)) << 11) + s;
                uint2 pk;
                pk.x = (unsigned)f2bf(v[0]) | ((unsigned)f2bf(v[1]) << 16);
                pk.y = (unsigned)f2bf(v[2]) | ((unsigned)f2bf(v[3]) << 16);
                *(uint2*)&outp[idx] = pk;
            } else {
                float* outp = (float*)outv;
#pragma unroll
                for (int r = 0; r < 4; ++r)
                    outp[(size_t)(mb + r) * DMODEL + n] = v[r];
            }
        }
}

#define QSCALE 0.1803368801111137f   // 0.125 * log2(e): scores come out in log2 units

__global__ __launch_bounds__(256)
void qkv_gemm_kernel(const unsigned short* __restrict__ xb, const unsigned short* __restrict__ wt,
                     const float* __restrict__ bq, const float* __restrict__ bk,
                     const float* __restrict__ bv,
                     unsigned short* __restrict__ Qb, unsigned short* __restrict__ Kb,
                     unsigned short* __restrict__ Vt)
{
    if (blockIdx.z == 0)      gemm_core<0>(xb, wt,                      bq, Qb, QSCALE);
    else if (blockIdx.z == 1) gemm_core<0>(xb, wt + DMODEL * DMODEL,     bk, Kb, 1.0f);
    else                      gemm_core<1>(xb, wt + 2 * DMODEL * DMODEL, bv, Vt, 1.0f);
}

__global__ __launch_bounds__(256)
void out_gemm_kernel(const unsigned short* __restrict__ ctx, const unsigned short* __restrict__ wt,
                     const float* __restrict__ bo, float* __restrict__ out)
{
    gemm_core<2>(ctx, wt + 3 * DMODEL * DMODEL, bo, out, 1.0f);
}

// ============ bf16 MFMA flash attention: KV=128 tiles, r5 double-buffer loop ============
// 512 thr = 8 waves, 32 q/wave. 16 KV tiles of 128, double-buffered __syncthreads.
// K tile [128 kv][64 dk] = 16K (128-B rows); V tile [64 dk][128 kv] = 16K (256-B rows).
// Body compute identical to r13 (raw exp2, lsum ones-MFMA, z16 C-in), 4 halves/tile.
__device__ __forceinline__
void attn_body4(const char* __restrict__ Kbuf, const char* __restrict__ Vbuf,
                const short8 (&qf)[4], const short8 ones, const f32x16& z16,
                f32x16 (&po)[2], f32x16& po_l,
                int q32, int hi, int swz)
{
#pragma unroll
    for (int hf = 0; hf < 4; ++hf) {
        // ---- S^T for kv rows [32*hf, 32*hf+32) ----
        short8 kf[4];
#pragma unroll
        for (int kk = 0; kk < 4; ++kk)
            kf[kk] = *(const short8*)(Kbuf + (hf * 32 + q32) * 128 + ((kk * 32 + hi * 16) ^ swz));
        __builtin_amdgcn_s_setprio(1);
        f32x16 s = __builtin_amdgcn_mfma_f32_32x32x16_bf16(kf[0], qf[0], z16, 0, 0, 0);
#pragma unroll
        for (int kk = 1; kk < 4; ++kk)
            s = __builtin_amdgcn_mfma_f32_32x32x16_bf16(kf[kk], qf[kk], s, 0, 0, 0);
        __builtin_amdgcn_s_setprio(0);

        // ---- p = 2^s (raw v_exp_f32; scores bounded, flush-to-zero correct) ----
#pragma unroll
        for (int r = 0; r < 16; ++r) s[r] = __builtin_amdgcn_exp2f(s[r]);

        // ---- PV B-fragments in-register (T12) ----
        short8 pf[2];
#pragma unroll
        for (int j = 0; j < 2; ++j) {
            const int bse = j * 8;
            unsigned wA0, wA1, wB0, wB1;
            asm("v_cvt_pk_bf16_f32 %0, %1, %2" : "=v"(wA0) : "v"(s[bse + 0]), "v"(s[bse + 1]));
            asm("v_cvt_pk_bf16_f32 %0, %1, %2" : "=v"(wA1) : "v"(s[bse + 2]), "v"(s[bse + 3]));
            asm("v_cvt_pk_bf16_f32 %0, %1, %2" : "=v"(wB0) : "v"(s[bse + 4]), "v"(s[bse + 5]));
            asm("v_cvt_pk_bf16_f32 %0, %1, %2" : "=v"(wB1) : "v"(s[bse + 6]), "v"(s[bse + 7]));
            asm volatile("v_permlane32_swap_b32 %0, %1" : "+v"(wA0), "+v"(wB0));
            asm volatile("v_permlane32_swap_b32 %0, %1" : "+v"(wA1), "+v"(wB1));
            union { unsigned u[4]; short8 s8; } pk;
            pk.u[0] = wA0; pk.u[1] = wA1; pk.u[2] = wB0; pk.u[3] = wB1;
            pf[j] = pk.s8;
        }

        // ---- PV + lsum-via-MFMA (V rows are 256 B: 128 kv cols) ----
        short8 vf0[2], vf1[2];
#pragma unroll
        for (int j = 0; j < 2; ++j) {
            const int ks = hf * 2 + j;            // 0..7 -> col bytes 0..224
            vf0[j] = *(const short8*)(Vbuf + q32 * 256 + ((ks * 32 + hi * 16) ^ swz));
            vf1[j] = *(const short8*)(Vbuf + (32 + q32) * 256 + ((ks * 32 + hi * 16) ^ swz));
        }
        __builtin_amdgcn_s_setprio(1);
#pragma unroll
        for (int j = 0; j < 2; ++j) {
            po[0] = __builtin_amdgcn_mfma_f32_32x32x16_bf16(vf0[j], pf[j], po[0], 0, 0, 0);
            po[1] = __builtin_amdgcn_mfma_f32_32x32x16_bf16(vf1[j], pf[j], po[1], 0, 0, 0);
            po_l  = __builtin_amdgcn_mfma_f32_32x32x16_bf16(ones,   pf[j], po_l,  0, 0, 0);
        }
        __builtin_amdgcn_s_setprio(0);
    }
}

__global__ __launch_bounds__(512)
void attn_kernel(const unsigned short* __restrict__ Qb, const unsigned short* __restrict__ Kb,
                 const unsigned short* __restrict__ Vt, unsigned short* __restrict__ ctx)
{
    __shared__ __align__(16) char smem[65536];   // K bufs [0,32K) x2 of 16K; V bufs [32K,64K) x2

    const int t   = threadIdx.x;
    const int l   = t & 63, w = t >> 6;
    const int q32 = l & 31, hi = l >> 5;
    const int swz = (q32 & 7) << 4;

    // XCD-aware swizzle (T1): each XCD gets 8 complete heads (K/V = 4MB = L2-resident).
    const int flat = (blockIdx.y << 3) | blockIdx.x;          // 0..511
    const int sid  = ((flat & 7) << 6) | (flat >> 3);
    const int qt = sid & 7;
    const int bh = sid >> 3;
    const int b  = bh >> 4, h = bh & 15;
    const int coln = h * DKDIM;

    const size_t qrow  = (size_t)b * SEQLEN + qt * 256 + w * 32 + q32;
    const size_t krow0 = (size_t)b * SEQLEN;
    const size_t vbase = (size_t)(b * NHEADS + h) * DKDIM * SEQLEN;

    // Q fragments in registers (pre-scaled by 0.125*log2e in projection)
    short8 qf[4];
#pragma unroll
    for (int kk = 0; kk < 4; ++kk)
        qf[kk] = *(const short8*)(Qb + qrow * DMODEL + coln + kk * 16 + hi * 8);

    short8 ones;
#pragma unroll
    for (int e = 0; e < 8; ++e) ones[e] = (short)0x3F80;   // bf16 1.0

    f32x16 z16;
#pragma unroll
    for (int r = 0; r < 16; ++r) z16[r] = 0.f;

    f32x16 po[2], po_l;
#pragma unroll
    for (int r = 0; r < 16; ++r) { po[0][r] = 0.f; po[1][r] = 0.f; po_l[r] = 0.f; }

    // staging addresses (per-thread, loop-invariant)
    const int so   = t << 4;              // 0..8191
    const int kr   = so >> 7;             // K dest row 0..63 (of 128), 128-B rows
    const int ksc  = (so & 127) ^ ((kr & 7) << 4);    // K src col bytes (also for row kr+64)
    const int vr   = so >> 8;             // V dest row 0..31 (of 64), 256-B rows
    const int vsc  = (so & 255) ^ ((vr & 7) << 4);    // V src col bytes (also for row vr+32)

#define KBUF(i) (smem + (i) * 16384)
#define VBUF(i) (smem + 32768 + (i) * 16384)
// KV tile kt covers kv rows [kt*128, kt*128+128)
#define STAGE(bufidx, kt)                                                                         \
    do {                                                                                          \
        gload16((const char*)Kb + (((krow0 + (kt) * 128 + kr)      * DMODEL + coln) << 1) + ksc,  \
                KBUF(bufidx) + so);                                                               \
        gload16((const char*)Kb + (((krow0 + (kt) * 128 + kr + 64) * DMODEL + coln) << 1) + ksc,  \
                KBUF(bufidx) + so + 8192);                                                        \
        gload16((const char*)Vt + ((vbase + (size_t)vr        * SEQLEN + (kt) * 128) << 1) + vsc, \
                VBUF(bufidx) + so);                                                               \
        gload16((const char*)Vt + ((vbase + (size_t)(vr + 32) * SEQLEN + (kt) * 128) << 1) + vsc, \
                VBUF(bufidx) + so + 8192);                                                        \
    } while (0)
#define BODY(bufidx)                                                            \
    attn_body4(KBUF(bufidx), VBUF(bufidx), qf, ones, z16, po, po_l, q32, hi, swz)

    // r5-verified double-buffer loop shape: stage-next, body, sync. 16 tiles, x2 unrolled.
    STAGE(0, 0);
    __syncthreads();                       // stage(0) drained

#pragma unroll 1
    for (int kt = 0; kt < 14; kt += 2) {
        STAGE(1, kt + 1);                  // tile kt+1 (odd) -> buf 1
        BODY(0);                           // tile kt from buf 0
        __syncthreads();                   // stage(kt+1) drained; buf0 reads done
        STAGE(0, kt + 2);                  // tile kt+2 (even) -> buf 0
        BODY(1);                           // tile kt+1 from buf 1
        __syncthreads();                   // stage(kt+2) drained; buf1 reads done
    }
    // tail: tile 14 (buf 0) staging 15 -> buf 1; then tile 15
    STAGE(1, 15);
    BODY(0);
    __syncthreads();
    BODY(1);

    __syncthreads();                      // before smem reuse in epilogue

    // ---- epilogue: normalize (lsum = po_l, all rows equal), transpose, write ----
    const float inv = 1.0f / po_l[0];
    char* T = smem + w * 4096;            // per-wave [32 q][64 d] bf16, swizzled
#pragma unroll
    for (int i = 0; i < 2; ++i)
#pragma unroll
        for (int g4 = 0; g4 < 4; ++g4) {
            const int d0 = i * 32 + g4 * 8 + hi * 4;
            uint2 pk;
            pk.x = (unsigned)f2bf(po[i][g4 * 4 + 0] * inv) | ((unsigned)f2bf(po[i][g4 * 4 + 1] * inv) << 16);
            pk.y = (unsigned)f2bf(po[i][g4 * 4 + 2] * inv) | ((unsigned)f2bf(po[i][g4 * 4 + 3] * inv) << 16);
            *(uint2*)(T + ((q32 * 128 + d0 * 2) ^ swz)) = pk;
        }
    __syncthreads();
#pragma unroll
    for (int pass = 0; pass < 4; ++pass) {
        const int o   = (l + pass * 64) << 4;    // 0..4095
        const int row = o >> 7;
        const int c   = o & 127;
        const uint4 val = *(const uint4*)(T + (o ^ ((row & 7) << 4)));
        const size_t token = (size_t)b * SEQLEN + qt * 256 + w * 32 + row;
        *(uint4*)&ctx[token * DMODEL + coln + (c >> 1)] = val;
    }
#undef STAGE
#undef BODY
#undef KBUF
#undef VBUF
}

extern "C" void kernel_launch(void* const* d_in, const int* in_sizes, int n_in,
                              void* d_out, int out_size, void* d_ws, size_t ws_size,
                              hipStream_t stream)
{
    const float* x  = (const float*)d_in[0];
    const float* Wq = (const float*)d_in[1];
    const float* bq = (const float*)d_in[2];
    const float* Wk = (const float*)d_in[3];
    const float* bk = (const float*)d_in[4];
    const float* Wv = (const float*)d_in[5];
    const float* bv = (const float*)d_in[6];
    const float* Wo = (const float*)d_in[7];
    const float* bo = (const float*)d_in[8];
    float* out = (float*)d_out;

    const size_t NE = (size_t)MTOT * DMODEL;
    unsigned short* xb  = (unsigned short*)d_ws;
    unsigned short* wt  = xb  + NE;
    unsigned short* Qb  = wt  + (size_t)4 * DMODEL * DMODEL;
    unsigned short* Kb  = Qb  + NE;
    unsigned short* Vt  = Kb  + NE;
    unsigned short* ctx = Vt  + NE;

    convert_all_kernel<<<dim3(4096 + 1024), 256, 0, stream>>>(x, Wq, Wk, Wv, Wo, xb, wt);
    qkv_gemm_kernel<<<dim3(8, 64, 3), 256, 0, stream>>>(xb, wt, bq, bk, bv, Qb, Kb, Vt);
    attn_kernel<<<dim3(SEQLEN / 256, NBATCH * NHEADS), dim3(512), 0, stream>>>(Qb, Kb, Vt, ctx);
    out_gemm_kernel<<<dim3(8, 64), 256, 0, stream>>>(ctx, wt, bo, out);
}